// Round 18
// baseline (127.014 us; speedup 1.0000x reference)
//
#include <hip/hip_runtime.h>
#include <math.h>

#define BB 4096        // batch size
#define DD 512         // repr dim
#define KTOP 9         // K+1
#define MARGIN_F 0.2f
#define NT 32          // 4096/128
#define NTRI (NT * (NT + 1) / 2)   // 528 upper-triangle 128x128 blocks

typedef __attribute__((ext_vector_type(8))) short short8;
typedef __attribute__((ext_vector_type(4))) float f32x4;
typedef unsigned long long u64;

__device__ unsigned short g_Rhi[(size_t)BB * DD];
__device__ u64 g_cmask[64 * 64];   // [class][lane] bit e -> label[j(lane,e)]==class

// ---- bf16 helper (RNE) ----
__device__ __forceinline__ unsigned short f2bf(float x) {
  unsigned u = __float_as_uint(x);
  u += 0x7fffu + ((u >> 16) & 1u);
  return (unsigned short)(u >> 16);
}

// ---- 16-bit ord: monotone map of f32, truncated; dequant mid-bucket ----
__device__ __forceinline__ float ord16val(unsigned o16) {
  unsigned e = (o16 << 16) | 0x8000u;
  unsigned s = (e & 0x80000000u) ? (e ^ 0x80000000u) : ~e;
  return __uint_as_float(s);
}

// ---- DPP wave reductions ----
__device__ __forceinline__ unsigned wavemax32_dpp(unsigned c) {
#define MSTEP(CTRL, RM)                                                        \
  {                                                                            \
    unsigned o = (unsigned)__builtin_amdgcn_update_dpp(0, (int)c, CTRL, RM, 0xf, false); \
    if (o > c) c = o;                                                          \
  }
  MSTEP(0xB1, 0xf) MSTEP(0x4E, 0xf) MSTEP(0x141, 0xf) MSTEP(0x140, 0xf)
  MSTEP(0x142, 0xa) MSTEP(0x143, 0xc)
#undef MSTEP
  return (unsigned)__builtin_amdgcn_readlane((int)c, 63);
}

__device__ __forceinline__ int wavesum_dpp(int c) {
#define SSTEP(CTRL, RM)                                                        \
  c += __builtin_amdgcn_update_dpp(0, c, CTRL, RM, 0xf, false);
  SSTEP(0xB1, 0xf) SSTEP(0x4E, 0xf) SSTEP(0x141, 0xf) SSTEP(0x140, 0xf)
  SSTEP(0x142, 0xa) SSTEP(0x143, 0xc)
#undef SSTEP
  return __builtin_amdgcn_readlane(c, 63);
}

__device__ __forceinline__ unsigned u4c(const uint4& f, int q) {
  return q == 0 ? f.x : q == 1 ? f.y : q == 2 ? f.z : f.w;
}

// ---------------- K0: split R -> bf16 hi + row sqnorms ----------------
__global__ __launch_bounds__(64) void splitsq(const float* __restrict__ R,
                                              float* __restrict__ sq) {
  const int row = blockIdx.x, lane = threadIdx.x;
  const float4* r4 = (const float4*)(R + (size_t)row * DD);
  float4 a = r4[lane], b = r4[lane + 64];
  float xs[8] = {a.x, a.y, a.z, a.w, b.x, b.y, b.z, b.w};
  unsigned short hs[8];
  float s = 0.f;
  #pragma unroll
  for (int q = 0; q < 8; ++q) {
    float x = xs[q];
    s += x * x;
    hs[q] = f2bf(x);
  }
  const size_t base = (size_t)row * DD;
  *(ushort4*)&g_Rhi[base + lane * 4]       = *(ushort4*)&hs[0];
  *(ushort4*)&g_Rhi[base + 256 + lane * 4] = *(ushort4*)&hs[4];
  #pragma unroll
  for (int off = 32; off; off >>= 1) s += __shfl_down(s, off);
  if (lane == 0) sq[row] = s;
}

// ---------------- K0b: per-class match bitmasks ----------------
// bit e of g_cmask[c][lane] <-> j = 512*(e>>3) + 8*lane + (e&7)  (u16-row layout)
__global__ __launch_bounds__(64) void buildmask(const int* __restrict__ labels) {
  __shared__ int slab[BB];
  const int c = blockIdx.x, lane = threadIdx.x;
  for (int i = lane; i < BB / 4; i += 64) ((int4*)slab)[i] = ((const int4*)labels)[i];
  __syncthreads();
  u64 m = 0;
  #pragma unroll
  for (int e = 0; e < 64; ++e) {
    int j = 512 * (e >> 3) + 8 * lane + (e & 7);
    m |= (u64)(slab[j] == c) << e;
  }
  g_cmask[c * 64 + lane] = m;
}

// ---------------- K1: 128x128 MFMA GEMM, BK=64 dbuf, REG-STAGING (no gload_lds) ----------------
// Cross-run model: stall tracked #global_load_lds/CU (~110-200 cyc each) across
// all 6 prior structures -- the LDS-DMA engine issue rate was the common wall.
// Reg-staging uses the normal (fully pipelined) load path: loads for step s+1
// issue BEFORE step s's MFMA (one step of HBM-latency cover), ds_write_b128
// lands them after; ONE barrier per step fences both hazards.
__global__ __launch_bounds__(256) void simgemm_rs(const int* __restrict__ labels,
                                                  const float* __restrict__ sq,
                                                  unsigned short* __restrict__ simq) {
  const int x = blockIdx.x & 7;      // XCD (round-robin dispatch)
  int c = blockIdx.x >> 3;           // 0..65 within XCD
  int bi = 0, bj = 0;
  #pragma unroll
  for (int q = 0; q < 4; ++q) {
    const int bjq = (q < 2) ? (2 * x + q) : (28 - 2 * x + q);   // {2x,2x+1,30-2x,31-2x}
    const int n = bjq + 1;
    if (c >= 0 && c < n) { bj = bjq; bi = c; }
    c -= n;
  }
  const int i0 = bi * 128, j0 = bj * 128;

  // union LDS: K-loop [buf][A|B][8192] u16 (64 KB) | epilogue T[128][132]+staging
  __shared__ __align__(16) unsigned char smembytes[65536];
  unsigned short (*kbuf)[2][8192] = (unsigned short (*)[2][8192])smembytes;

  const int tid = threadIdx.x;
  const int wid = tid >> 6, lane = tid & 63;
  const int wr = wid >> 1, wc = wid & 1;
  const int lrow = lane & 15, kblk = lane >> 4;

  const int sr = lane & 15;
  const int sc = (lane >> 4) * 8;

  f32x4 acc[4][4] = {};
  uint4 rg[8];

  auto stage_load = [&](int k0) {
    #pragma unroll
    for (int i = 0; i < 2; ++i) {
      const int r = (2 * wid + i) * 16 + sr;
      #pragma unroll
      for (int s = 0; s < 2; ++s) {
        rg[i * 4 + s * 2 + 0] = *(const uint4*)&g_Rhi[(size_t)(i0 + r) * DD + k0 + s * 32 + sc];
        rg[i * 4 + s * 2 + 1] = *(const uint4*)&g_Rhi[(size_t)(j0 + r) * DD + k0 + s * 32 + sc];
      }
    }
  };
  auto stage_write = [&](int buf) {
    const int loff = lane * 8;   // u16 units = 16 B/lane
    #pragma unroll
    for (int i = 0; i < 2; ++i) {
      const int chunk = 2 * wid + i;
      #pragma unroll
      for (int s = 0; s < 2; ++s) {
        *(uint4*)&kbuf[buf][0][chunk * 1024 + s * 512 + loff] = rg[i * 4 + s * 2 + 0];
        *(uint4*)&kbuf[buf][1][chunk * 1024 + s * 512 + loff] = rg[i * 4 + s * 2 + 1];
      }
    }
  };

  stage_load(0);
  stage_write(0);
  stage_load(64);        // step-1 data rides in regs under step-0 compute
  __syncthreads();       // buf0 visible to all waves

  for (int step = 0; step < 8; ++step) {
    const int cur = step & 1;

    #pragma unroll
    for (int kk = 0; kk < 2; ++kk) {
      short8 a[4], b[4];
      #pragma unroll
      for (int m = 0; m < 4; ++m)
        a[m] = *(const short8*)&kbuf[cur][0][(wr * 4 + m) * 1024 + kk * 512 + lane * 8];
      #pragma unroll
      for (int n = 0; n < 4; ++n)
        b[n] = *(const short8*)&kbuf[cur][1][(wc * 4 + n) * 1024 + kk * 512 + lane * 8];
      #pragma unroll
      for (int m = 0; m < 4; ++m) {
        #pragma unroll
        for (int n = 0; n < 4; ++n) {
          acc[m][n] = __builtin_amdgcn_mfma_f32_16x16x32_bf16(a[m], b[n], acc[m][n], 0, 0, 0);
        }
      }
    }

    if (step < 7) {
      stage_write(cur ^ 1);                      // step+1 data -> other buffer
      if (step < 6) stage_load((step + 2) * 64); // prefetch next-next into regs
      __syncthreads();                           // writes visible; fences reuse
    }
  }

  // ---- epilogue: quantize to u16 ord into LDS T[128][132], coalesced dual store ----
  __syncthreads();
  unsigned short (*T)[132] = (unsigned short (*)[132])smembytes;   // 33792 B
  float* sqi = (float*)(smembytes + 33792);
  float* sqj = (float*)(smembytes + 34304);
  int* labi  = (int*)(smembytes + 34816);
  int* labj  = (int*)(smembytes + 35328);
  if (tid < 128) { sqi[tid] = sq[i0 + tid]; labi[tid] = labels[i0 + tid]; }
  else { int t2 = tid - 128; sqj[t2] = sq[j0 + t2]; labj[t2] = labels[j0 + t2]; }
  __syncthreads();

  #pragma unroll
  for (int m = 0; m < 4; ++m) {
    const int rbase = wr * 64 + m * 16 + kblk * 4;
    #pragma unroll
    for (int n = 0; n < 4; ++n) {
      const int ccol = wc * 64 + n * 16 + lrow;
      const float sqc = sqj[ccol];
      const int lc_ = labj[ccol];
      #pragma unroll
      for (int reg = 0; reg < 4; ++reg) {
        const int r = rbase + reg;
        float res = sqi[r] - 2.0f * acc[m][n][reg] + sqc;
        float dd = (res <= 0.f) ? 0.f : sqrtf(res);
        float sv = -dd + ((labi[r] != lc_) ? MARGIN_F : 0.f);
        unsigned su = __float_as_uint(sv);
        unsigned ord = su ^ ((unsigned)((int)su >> 31) | 0x80000000u);
        T[r][ccol] = (unsigned short)(ord >> 16);
      }
    }
  }
  __syncthreads();

  // straight store: 8 passes x 16 rows; each row 256 B = 16 lanes x 16 B
  const int srow0 = tid >> 4, scol0 = (tid & 15) * 8;
  #pragma unroll
  for (int p = 0; p < 8; ++p) {
    const int r = p * 16 + srow0;
    short8 w = *(const short8*)&T[r][scol0];
    *(short8*)&simq[(size_t)(i0 + r) * BB + j0 + scol0] = w;
  }
  if (bi != bj) {
    #pragma unroll
    for (int p = 0; p < 8; ++p) {
      const int col = p * 16 + srow0;        // output row j0+col
      unsigned short tmp[8];
      #pragma unroll
      for (int t = 0; t < 8; ++t) tmp[t] = T[scol0 + t][col];
      *(short8*)&simq[(size_t)(j0 + col) * BB + i0 + scol0] = *(short8*)tmp;
    }
  }
}

// ---------------- K2: wave-per-row rank processing, PRECOMPUTED u32 keys ----------------
// Element e (0..63) of lane: j = 512*(e>>3) + 8*lane + (e&7).
// key = ord16<<13 | (4095-j)<<1 | match -- built ONCE at load; scan passes
// are compare-only.
#define TOP2UPD(k, a, b) {                                                     \
  unsigned _mx = ((k) > (a)) ? (k) : (a);                                      \
  unsigned _mn = ((k) > (a)) ? (a) : (k);                                      \
  (a) = _mx;                                                                   \
  (b) = (_mn > (b)) ? _mn : (b); }

__global__ __launch_bounds__(256) void rowproc7(const unsigned short* __restrict__ simq,
                                                const int* __restrict__ labels,
                                                float* __restrict__ partials) {
  const int tid = threadIdx.x;
  const int lane = tid & 63;
  const int row = blockIdx.x * 4 + (tid >> 6);

  const int myl = labels[row];
  const u64 mask = g_cmask[myl * 64 + lane];
  const unsigned lbase2 = (unsigned)((4095 - 8 * lane) << 1);

  const uint4* rowp = (const uint4*)(simq + (size_t)row * BB);
  unsigned k[64];
  #pragma unroll
  for (int s = 0; s < 8; ++s) {
    uint4 w = rowp[lane + s * 64];
    const unsigned base_s = lbase2 - (unsigned)(1024 * s);
    #pragma unroll
    for (int q = 0; q < 4; ++q) {
      const unsigned wv = u4c(w, q);
      const int e0 = s * 8 + q * 2;
      k[e0]     = ((wv & 0xffffu) << 13)
                | (base_s - (unsigned)((q * 2) << 1)     + (unsigned)((mask >> e0) & 1ull));
      k[e0 + 1] = ((wv >> 16) << 13)
                | (base_s - (unsigned)((q * 2 + 1) << 1) + (unsigned)((mask >> (e0 + 1)) & 1ull));
    }
  }

  unsigned h1 = 0, h2 = 0;
  #pragma unroll
  for (int e = 0; e < 64; ++e) TOP2UPD(k[e], h1, h2);
  const int pos = wavesum_dpp(__popcll(mask));
  const int ks = min(pos, KTOP);

  unsigned kth = 0;
  float fp = 0.f; int fpn = 0;
  #pragma unroll
  for (int t = 0; t < KTOP; ++t) {
    if (t < ks) {
      unsigned g = wavemax32_dpp(h1);
      if (!(g & 1u)) { fp += ord16val(g >> 13) * (1.f / log2f((float)(t + 2)) + 1.f); fpn++; }
      if (t == ks - 1) kth = g;
      if (h1 == g) {
        h1 = h2; h2 = ~0u;
        if (h1 == ~0u) {
          h1 = 0; h2 = 0;
          #pragma unroll
          for (int e = 0; e < 64; ++e) {
            if (k[e] < g) TOP2UPD(k[e], h1, h2);
          }
        }
      }
    }
  }

  float fn = 0.f;
  if (fpn > 0) {
    unsigned f1 = 0, f2 = 0;
    #pragma unroll
    for (int e = 0; e < 64; ++e) {
      if ((k[e] & 1u) && k[e] < kth) TOP2UPD(k[e], f1, f2);
    }
    unsigned ck[KTOP];
    int nc = 0;
    #pragma unroll
    for (int u = 0; u < KTOP; ++u) {
      ck[u] = ~0u;
      if (u < fpn) {
        unsigned g = wavemax32_dpp(f1);
        if (g != 0u) {
          ck[u] = g; nc = u + 1;
          if (f1 == g) {
            f1 = f2; f2 = ~0u;
            if (f1 == ~0u) {
              f1 = 0; f2 = 0;
              #pragma unroll
              for (int e = 0; e < 64; ++e) {
                if ((k[e] & 1u) && k[e] < g) TOP2UPD(k[e], f1, f2);
              }
            }
          }
        }
      }
    }
    if (nc > 0) {
      int cnt[KTOP];
      #pragma unroll
      for (int u = 0; u < KTOP; ++u) cnt[u] = 0;
      #pragma unroll
      for (int e = 0; e < 64; ++e) {
        #pragma unroll
        for (int u = 0; u < KTOP; ++u) cnt[u] += (k[e] > ck[u]) ? 1 : 0;
      }
      #pragma unroll
      for (int u = 0; u < KTOP; ++u) cnt[u] = wavesum_dpp(cnt[u]);
      #pragma unroll
      for (int u = 0; u < KTOP; ++u) {
        if (u < nc) {
          int rank = 1 + cnt[u];
          fn += ord16val(ck[u] >> 13) * (1.f / log2f((float)(rank + 1)) + 1.f);
        }
      }
    }
  }

  if (lane == 0) partials[row] = fp - fn;
}

// ---------------- K3: deterministic final reduction ----------------
__global__ __launch_bounds__(256) void finalreduce(const float* __restrict__ partials,
                                                   float* __restrict__ out) {
  __shared__ float s[256];
  const int tid = threadIdx.x;
  float acc = 0.f;
  for (int j = tid; j < BB; j += 256) acc += partials[j];
  s[tid] = acc; __syncthreads();
  #pragma unroll
  for (int st = 128; st; st >>= 1) { if (tid < st) s[tid] += s[tid + st]; __syncthreads(); }
  if (tid == 0) out[0] = s[0];
}

extern "C" void kernel_launch(void* const* d_in, const int* in_sizes, int n_in,
                              void* d_out, int out_size, void* d_ws, size_t ws_size,
                              hipStream_t stream) {
  const float* R      = (const float*)d_in[0];
  const int*   labels = (const int*)d_in[1];
  float* out = (float*)d_out;

  unsigned short* simq = (unsigned short*)d_ws;                          // 32 MB
  float* sq            = (float*)((char*)d_ws + (size_t)BB * BB * 2);    // 16 KB
  float* partials      = sq + BB;                                        // 16 KB

  splitsq<<<BB, 64, 0, stream>>>(R, sq);
  buildmask<<<64, 64, 0, stream>>>(labels);
  simgemm_rs<<<NTRI, 256, 0, stream>>>(labels, sq, simq);
  rowproc7<<<BB / 4, 256, 0, stream>>>(simq, labels, partials);
  finalreduce<<<1, 256, 0, stream>>>(partials, out);
}

// Round 19
// 93.883 us; speedup vs baseline: 1.3529x; 1.3529x over previous
//
#include <hip/hip_runtime.h>
#include <math.h>

#define BB 4096        // batch size
#define DD 512         // repr dim
#define KTOP 9         // K+1
#define MARGIN_F 0.2f
#define NT 32          // 4096/128
#define NTRI (NT * (NT + 1) / 2)   // 528 upper-triangle 128x128 blocks

typedef __attribute__((ext_vector_type(8))) short short8;
typedef __attribute__((ext_vector_type(4))) float f32x4;
typedef unsigned long long u64;

__device__ unsigned short g_Rhi[(size_t)BB * DD];
__device__ u64 g_cmask[64 * 64];   // [class][lane] bit e -> label[j(lane,e)]==class

// ---- bf16 helper (RNE) ----
__device__ __forceinline__ unsigned short f2bf(float x) {
  unsigned u = __float_as_uint(x);
  u += 0x7fffu + ((u >> 16) & 1u);
  return (unsigned short)(u >> 16);
}

// ---- 16-bit ord: monotone map of f32, truncated; dequant mid-bucket ----
__device__ __forceinline__ float ord16val(unsigned o16) {
  unsigned e = (o16 << 16) | 0x8000u;
  unsigned s = (e & 0x80000000u) ? (e ^ 0x80000000u) : ~e;
  return __uint_as_float(s);
}

// ---- DPP wave reductions ----
__device__ __forceinline__ unsigned wavemax32_dpp(unsigned c) {
#define MSTEP(CTRL, RM)                                                        \
  {                                                                            \
    unsigned o = (unsigned)__builtin_amdgcn_update_dpp(0, (int)c, CTRL, RM, 0xf, false); \
    if (o > c) c = o;                                                          \
  }
  MSTEP(0xB1, 0xf) MSTEP(0x4E, 0xf) MSTEP(0x141, 0xf) MSTEP(0x140, 0xf)
  MSTEP(0x142, 0xa) MSTEP(0x143, 0xc)
#undef MSTEP
  return (unsigned)__builtin_amdgcn_readlane((int)c, 63);
}

__device__ __forceinline__ int wavesum_dpp(int c) {
#define SSTEP(CTRL, RM)                                                        \
  c += __builtin_amdgcn_update_dpp(0, c, CTRL, RM, 0xf, false);
  SSTEP(0xB1, 0xf) SSTEP(0x4E, 0xf) SSTEP(0x141, 0xf) SSTEP(0x140, 0xf)
  SSTEP(0x142, 0xa) SSTEP(0x143, 0xc)
#undef SSTEP
  return __builtin_amdgcn_readlane(c, 63);
}

__device__ __forceinline__ unsigned u4c(const uint4& f, int q) {
  return q == 0 ? f.x : q == 1 ? f.y : q == 2 ? f.z : f.w;
}

// ---------------- K0: split R -> bf16 hi + row sqnorms ----------------
__global__ __launch_bounds__(64) void splitsq(const float* __restrict__ R,
                                              float* __restrict__ sq) {
  const int row = blockIdx.x, lane = threadIdx.x;
  const float4* r4 = (const float4*)(R + (size_t)row * DD);
  float4 a = r4[lane], b = r4[lane + 64];
  float xs[8] = {a.x, a.y, a.z, a.w, b.x, b.y, b.z, b.w};
  unsigned short hs[8];
  float s = 0.f;
  #pragma unroll
  for (int q = 0; q < 8; ++q) {
    float x = xs[q];
    s += x * x;
    hs[q] = f2bf(x);
  }
  const size_t base = (size_t)row * DD;
  *(ushort4*)&g_Rhi[base + lane * 4]       = *(ushort4*)&hs[0];
  *(ushort4*)&g_Rhi[base + 256 + lane * 4] = *(ushort4*)&hs[4];
  #pragma unroll
  for (int off = 32; off; off >>= 1) s += __shfl_down(s, off);
  if (lane == 0) sq[row] = s;
}

// ---------------- K0b: per-class match bitmasks ----------------
// bit e of g_cmask[c][lane] <-> j = 512*(e>>3) + 8*lane + (e&7)  (u16-row layout)
__global__ __launch_bounds__(64) void buildmask(const int* __restrict__ labels) {
  __shared__ int slab[BB];
  const int c = blockIdx.x, lane = threadIdx.x;
  for (int i = lane; i < BB / 4; i += 64) ((int4*)slab)[i] = ((const int4*)labels)[i];
  __syncthreads();
  u64 m = 0;
  #pragma unroll
  for (int e = 0; e < 64; ++e) {
    int j = 512 * (e >> 3) + 8 * lane + (e & 7);
    m |= (u64)(slab[j] == c) << e;
  }
  g_cmask[c * 64 + lane] = m;
}

// ---------------- K1: 128x128 MFMA GEMM, BK=64 dbuf, reg-staging (spill-proofed) ----------------
// R17's structure was never tested: compiler spilled the staging regs (VGPR=88,
// +72 MB scratch writes). Fix: __launch_bounds__(256,2) (LDS caps residency at
// 2 blocks/CU anyway) + 8 explicitly-NAMED uint4 staging registers. One barrier
// per step: compute(cur) -> ds_write(next) -> gload(step+2)->regs -> barrier.
__global__ __launch_bounds__(256, 2) void simgemm_rs2(const int* __restrict__ labels,
                                                      const float* __restrict__ sq,
                                                      unsigned short* __restrict__ simq) {
  const int x = blockIdx.x & 7;      // XCD (round-robin dispatch)
  int c = blockIdx.x >> 3;           // 0..65 within XCD
  int bi = 0, bj = 0;
  #pragma unroll
  for (int q = 0; q < 4; ++q) {
    const int bjq = (q < 2) ? (2 * x + q) : (28 - 2 * x + q);   // {2x,2x+1,30-2x,31-2x}
    const int n = bjq + 1;
    if (c >= 0 && c < n) { bj = bjq; bi = c; }
    c -= n;
  }
  const int i0 = bi * 128, j0 = bj * 128;

  // union LDS: K-loop [buf][A|B][8192] u16 (64 KB) | epilogue T[128][132]+staging
  __shared__ __align__(16) unsigned char smembytes[65536];
  unsigned short (*kbuf)[2][8192] = (unsigned short (*)[2][8192])smembytes;

  const int tid = threadIdx.x;
  const int wid = tid >> 6, lane = tid & 63;
  const int wr = wid >> 1, wc = wid & 1;
  const int lrow = lane & 15, kblk = lane >> 4;

  const int sr = lane & 15;
  const int sc = (lane >> 4) * 8;
  const int r0 = (2 * wid + 0) * 16 + sr;         // chunk rows
  const int r1 = (2 * wid + 1) * 16 + sr;
  const unsigned short* gA0 = &g_Rhi[(size_t)(i0 + r0) * DD + sc];
  const unsigned short* gA1 = &g_Rhi[(size_t)(i0 + r1) * DD + sc];
  const unsigned short* gB0 = &g_Rhi[(size_t)(j0 + r0) * DD + sc];
  const unsigned short* gB1 = &g_Rhi[(size_t)(j0 + r1) * DD + sc];

  f32x4 acc[4][4] = {};
  // named staging regs: [chunk 0/1][k-half 0/1][A/B]
  uint4 vA00, vA01, vA10, vA11, vB00, vB01, vB10, vB11;

#define STAGE_LOAD(K0)                                                         \
  vA00 = *(const uint4*)(gA0 + (K0));      vB00 = *(const uint4*)(gB0 + (K0)); \
  vA01 = *(const uint4*)(gA0 + (K0) + 32); vB01 = *(const uint4*)(gB0 + (K0) + 32); \
  vA10 = *(const uint4*)(gA1 + (K0));      vB10 = *(const uint4*)(gB1 + (K0)); \
  vA11 = *(const uint4*)(gA1 + (K0) + 32); vB11 = *(const uint4*)(gB1 + (K0) + 32);

#define STAGE_WRITE(BUF)                                                       \
  {                                                                            \
    const int c0 = (2 * wid + 0) * 1024 + lane * 8;                            \
    const int c1 = (2 * wid + 1) * 1024 + lane * 8;                            \
    *(uint4*)&kbuf[BUF][0][c0]       = vA00; *(uint4*)&kbuf[BUF][1][c0]       = vB00; \
    *(uint4*)&kbuf[BUF][0][c0 + 512] = vA01; *(uint4*)&kbuf[BUF][1][c0 + 512] = vB01; \
    *(uint4*)&kbuf[BUF][0][c1]       = vA10; *(uint4*)&kbuf[BUF][1][c1]       = vB10; \
    *(uint4*)&kbuf[BUF][0][c1 + 512] = vA11; *(uint4*)&kbuf[BUF][1][c1 + 512] = vB11; \
  }

  STAGE_LOAD(0);
  STAGE_WRITE(0);
  STAGE_LOAD(64);        // step-1 data rides in regs under step-0 compute
  __syncthreads();       // buf0 visible to all waves

  for (int step = 0; step < 8; ++step) {
    const int cur = step & 1;

    #pragma unroll
    for (int kk = 0; kk < 2; ++kk) {
      short8 a[4], b[4];
      #pragma unroll
      for (int m = 0; m < 4; ++m)
        a[m] = *(const short8*)&kbuf[cur][0][(wr * 4 + m) * 1024 + kk * 512 + lane * 8];
      #pragma unroll
      for (int n = 0; n < 4; ++n)
        b[n] = *(const short8*)&kbuf[cur][1][(wc * 4 + n) * 1024 + kk * 512 + lane * 8];
      #pragma unroll
      for (int m = 0; m < 4; ++m) {
        #pragma unroll
        for (int n = 0; n < 4; ++n) {
          acc[m][n] = __builtin_amdgcn_mfma_f32_16x16x32_bf16(a[m], b[n], acc[m][n], 0, 0, 0);
        }
      }
    }

    if (step < 7) {
      STAGE_WRITE(cur ^ 1);                        // step+1 data -> other buffer
      if (step < 6) { STAGE_LOAD((step + 2) * 64); } // prefetch next-next into regs
      __syncthreads();                             // writes visible; fences buffer reuse
    }
  }
#undef STAGE_LOAD
#undef STAGE_WRITE

  // ---- epilogue: quantize to u16 ord into LDS T[128][132], coalesced dual store ----
  __syncthreads();
  unsigned short (*T)[132] = (unsigned short (*)[132])smembytes;   // 33792 B
  float* sqi = (float*)(smembytes + 33792);
  float* sqj = (float*)(smembytes + 34304);
  int* labi  = (int*)(smembytes + 34816);
  int* labj  = (int*)(smembytes + 35328);
  if (tid < 128) { sqi[tid] = sq[i0 + tid]; labi[tid] = labels[i0 + tid]; }
  else { int t2 = tid - 128; sqj[t2] = sq[j0 + t2]; labj[t2] = labels[j0 + t2]; }
  __syncthreads();

  #pragma unroll
  for (int m = 0; m < 4; ++m) {
    const int rbase = wr * 64 + m * 16 + kblk * 4;
    #pragma unroll
    for (int n = 0; n < 4; ++n) {
      const int ccol = wc * 64 + n * 16 + lrow;
      const float sqc = sqj[ccol];
      const int lc_ = labj[ccol];
      #pragma unroll
      for (int reg = 0; reg < 4; ++reg) {
        const int r = rbase + reg;
        float res = sqi[r] - 2.0f * acc[m][n][reg] + sqc;
        float dd = (res <= 0.f) ? 0.f : sqrtf(res);
        float sv = -dd + ((labi[r] != lc_) ? MARGIN_F : 0.f);
        unsigned su = __float_as_uint(sv);
        unsigned ord = su ^ ((unsigned)((int)su >> 31) | 0x80000000u);
        T[r][ccol] = (unsigned short)(ord >> 16);
      }
    }
  }
  __syncthreads();

  // straight store: 8 passes x 16 rows; each row 256 B = 16 lanes x 16 B
  const int srow0 = tid >> 4, scol0 = (tid & 15) * 8;
  #pragma unroll
  for (int p = 0; p < 8; ++p) {
    const int r = p * 16 + srow0;
    short8 w = *(const short8*)&T[r][scol0];
    *(short8*)&simq[(size_t)(i0 + r) * BB + j0 + scol0] = w;
  }
  if (bi != bj) {
    #pragma unroll
    for (int p = 0; p < 8; ++p) {
      const int col = p * 16 + srow0;        // output row j0+col
      unsigned short tmp[8];
      #pragma unroll
      for (int t = 0; t < 8; ++t) tmp[t] = T[scol0 + t][col];
      *(short8*)&simq[(size_t)(j0 + col) * BB + i0 + scol0] = *(short8*)tmp;
    }
  }
}

// ---------------- K2: wave-per-row rank processing, PRECOMPUTED u32 keys ----------------
// Element e (0..63) of lane: j = 512*(e>>3) + 8*lane + (e&7).
// key = ord16<<13 | (4095-j)<<1 | match -- built ONCE at load; scan passes
// are compare-only.
#define TOP2UPD(k, a, b) {                                                     \
  unsigned _mx = ((k) > (a)) ? (k) : (a);                                      \
  unsigned _mn = ((k) > (a)) ? (a) : (k);                                      \
  (a) = _mx;                                                                   \
  (b) = (_mn > (b)) ? _mn : (b); }

__global__ __launch_bounds__(256) void rowproc7(const unsigned short* __restrict__ simq,
                                                const int* __restrict__ labels,
                                                float* __restrict__ partials) {
  const int tid = threadIdx.x;
  const int lane = tid & 63;
  const int row = blockIdx.x * 4 + (tid >> 6);

  const int myl = labels[row];
  const u64 mask = g_cmask[myl * 64 + lane];
  const unsigned lbase2 = (unsigned)((4095 - 8 * lane) << 1);

  const uint4* rowp = (const uint4*)(simq + (size_t)row * BB);
  unsigned k[64];
  #pragma unroll
  for (int s = 0; s < 8; ++s) {
    uint4 w = rowp[lane + s * 64];
    const unsigned base_s = lbase2 - (unsigned)(1024 * s);
    #pragma unroll
    for (int q = 0; q < 4; ++q) {
      const unsigned wv = u4c(w, q);
      const int e0 = s * 8 + q * 2;
      k[e0]     = ((wv & 0xffffu) << 13)
                | (base_s - (unsigned)((q * 2) << 1)     + (unsigned)((mask >> e0) & 1ull));
      k[e0 + 1] = ((wv >> 16) << 13)
                | (base_s - (unsigned)((q * 2 + 1) << 1) + (unsigned)((mask >> (e0 + 1)) & 1ull));
    }
  }

  unsigned h1 = 0, h2 = 0;
  #pragma unroll
  for (int e = 0; e < 64; ++e) TOP2UPD(k[e], h1, h2);
  const int pos = wavesum_dpp(__popcll(mask));
  const int ks = min(pos, KTOP);

  unsigned kth = 0;
  float fp = 0.f; int fpn = 0;
  #pragma unroll
  for (int t = 0; t < KTOP; ++t) {
    if (t < ks) {
      unsigned g = wavemax32_dpp(h1);
      if (!(g & 1u)) { fp += ord16val(g >> 13) * (1.f / log2f((float)(t + 2)) + 1.f); fpn++; }
      if (t == ks - 1) kth = g;
      if (h1 == g) {
        h1 = h2; h2 = ~0u;
        if (h1 == ~0u) {
          h1 = 0; h2 = 0;
          #pragma unroll
          for (int e = 0; e < 64; ++e) {
            if (k[e] < g) TOP2UPD(k[e], h1, h2);
          }
        }
      }
    }
  }

  float fn = 0.f;
  if (fpn > 0) {
    unsigned f1 = 0, f2 = 0;
    #pragma unroll
    for (int e = 0; e < 64; ++e) {
      if ((k[e] & 1u) && k[e] < kth) TOP2UPD(k[e], f1, f2);
    }
    unsigned ck[KTOP];
    int nc = 0;
    #pragma unroll
    for (int u = 0; u < KTOP; ++u) {
      ck[u] = ~0u;
      if (u < fpn) {
        unsigned g = wavemax32_dpp(f1);
        if (g != 0u) {
          ck[u] = g; nc = u + 1;
          if (f1 == g) {
            f1 = f2; f2 = ~0u;
            if (f1 == ~0u) {
              f1 = 0; f2 = 0;
              #pragma unroll
              for (int e = 0; e < 64; ++e) {
                if ((k[e] & 1u) && k[e] < g) TOP2UPD(k[e], f1, f2);
              }
            }
          }
        }
      }
    }
    if (nc > 0) {
      int cnt[KTOP];
      #pragma unroll
      for (int u = 0; u < KTOP; ++u) cnt[u] = 0;
      #pragma unroll
      for (int e = 0; e < 64; ++e) {
        #pragma unroll
        for (int u = 0; u < KTOP; ++u) cnt[u] += (k[e] > ck[u]) ? 1 : 0;
      }
      #pragma unroll
      for (int u = 0; u < KTOP; ++u) cnt[u] = wavesum_dpp(cnt[u]);
      #pragma unroll
      for (int u = 0; u < KTOP; ++u) {
        if (u < nc) {
          int rank = 1 + cnt[u];
          fn += ord16val(ck[u] >> 13) * (1.f / log2f((float)(rank + 1)) + 1.f);
        }
      }
    }
  }

  if (lane == 0) partials[row] = fp - fn;
}

// ---------------- K3: deterministic final reduction ----------------
__global__ __launch_bounds__(256) void finalreduce(const float* __restrict__ partials,
                                                   float* __restrict__ out) {
  __shared__ float s[256];
  const int tid = threadIdx.x;
  float acc = 0.f;
  for (int j = tid; j < BB; j += 256) acc += partials[j];
  s[tid] = acc; __syncthreads();
  #pragma unroll
  for (int st = 128; st; st >>= 1) { if (tid < st) s[tid] += s[tid + st]; __syncthreads(); }
  if (tid == 0) out[0] = s[0];
}

extern "C" void kernel_launch(void* const* d_in, const int* in_sizes, int n_in,
                              void* d_out, int out_size, void* d_ws, size_t ws_size,
                              hipStream_t stream) {
  const float* R      = (const float*)d_in[0];
  const int*   labels = (const int*)d_in[1];
  float* out = (float*)d_out;

  unsigned short* simq = (unsigned short*)d_ws;                          // 32 MB
  float* sq            = (float*)((char*)d_ws + (size_t)BB * BB * 2);    // 16 KB
  float* partials      = sq + BB;                                        // 16 KB

  splitsq<<<BB, 64, 0, stream>>>(R, sq);
  buildmask<<<64, 64, 0, stream>>>(labels);
  simgemm_rs2<<<NTRI, 256, 0, stream>>>(labels, sq, simq);
  rowproc7<<<BB / 4, 256, 0, stream>>>(simq, labels, partials);
  finalreduce<<<1, 256, 0, stream>>>(partials, out);
}